// Round 8
// baseline (1098.789 us; speedup 1.0000x reference)
//
#include <hip/hip_runtime.h>
#include <math.h>

#define NJ 17
#define XS 132      // fp32 row stride for sX (floats)
#define LBS 264     // ushort row stride for sLb/sRb
#define XBS 136     // ushort row stride for xh/xl/sVb rows (16B-aligned)
#define SS 17       // score row stride (floats)
#define TOKE (NJ*128)

typedef unsigned short ushort_t;
typedef unsigned int uint_t;
typedef __attribute__((ext_vector_type(8))) short short8;
typedef __attribute__((ext_vector_type(4))) float f32x4;

// adjacency bitmasks (both dirs + diag)
__device__ __constant__ unsigned int ADJM[NJ] = {
    0x93u, 0x7u, 0xEu, 0xCu, 0x31u, 0x70u, 0x60u,
    0x181u, 0x4B80u, 0x700u, 0x600u, 0x1900u, 0x3800u, 0x3000u,
    0xC100u, 0x1C000u, 0x18000u
};
// dense list of the 49 adjacent (i,j) pairs, packed (i<<8)|j
__device__ __constant__ unsigned short PAIR[49] = {
    0x0000,0x0001,0x0004,0x0007, 0x0100,0x0101,0x0102, 0x0201,0x0202,0x0203,
    0x0302,0x0303, 0x0400,0x0404,0x0405, 0x0504,0x0505,0x0506, 0x0605,0x0606,
    0x0700,0x0707,0x0708, 0x0807,0x0808,0x0809,0x080B,0x080E, 0x0908,0x0909,0x090A,
    0x0A09,0x0A0A, 0x0B08,0x0B0B,0x0B0C, 0x0C0B,0x0C0C,0x0C0D, 0x0D0C,0x0D0D,
    0x0E08,0x0E0E,0x0E0F, 0x0F0E,0x0F0F,0x0F10, 0x100F,0x1010
};

__device__ __forceinline__ uint_t f2bf(float v){
    uint_t u = __float_as_uint(v);
    return (u + 0x7FFFu + ((u >> 16) & 1u)) >> 16;
}
__device__ __forceinline__ float bf2f(uint_t h){ return __uint_as_float(h << 16); }
__device__ __forceinline__ float bflo(uint_t u){ return __uint_as_float(u << 16); }
__device__ __forceinline__ float bfhi(uint_t u){ return __uint_as_float(u & 0xFFFF0000u); }
__device__ __forceinline__ float lrelu02(float u){ return fmaxf(u, 0.f) + 0.2f*fminf(u, 0.f); }
__device__ __forceinline__ float gelu_exact(float x){ return 0.5f*x*(1.f + erff(x*0.70710678118654752f)); }

// prep: WT[f][k] bf16 hi/lo (f: 0..255 w1-col, 256..511 w2-col, 512..639 vw-col) + bcat
__global__ void prep_kernel(const float* __restrict__ w1, const float* __restrict__ b1,
                            const float* __restrict__ w2, const float* __restrict__ b2,
                            const float* __restrict__ vw, const float* __restrict__ vb,
                            ushort_t* __restrict__ whi, ushort_t* __restrict__ wlo,
                            float* __restrict__ bcat){
    int gid = blockIdx.x*256 + threadIdx.x;
    if (gid < 640*128){
        int f = gid >> 7, k = gid & 127;
        float v;
        if (f < 256)      v = w1[k*256 + f];
        else if (f < 512) v = w2[k*256 + (f-256)];
        else              v = vw[k*128 + (f-512)];
        uint_t h = f2bf(v);
        whi[gid] = (ushort_t)h;
        wlo[gid] = (ushort_t)f2bf(v - bf2f(h));
    }
    if (gid < 640){
        float b;
        if (gid < 256)      b = b1[gid];
        else if (gid < 512) b = b2[gid-256];
        else                b = vb[gid-512];
        bcat[gid] = b;
    }
}

// r8: VGPR-reduction round. Occupancy model from r0..r7 counters:
//   waves/SIMD = floor(~256 / VGPR_Count)  (VGPR 80 -> 3 waves; 100-128 -> 2).
// Two register offloads (numerics-identical):
//   (1) three-pass (b): one B-fragment set (32 VGPR) live at a time, W re-streamed
//       from L2 per pass; region B laid out per-token so overlay writes never hit
//       the next pass's operands; row-16 fragments from a 1KB stash written by (a).
//   (2) x0 kept in `out` (global, L3-resident) instead of 20 VGPRs; final store
//       overwrites.
// LDS 12,108 f = 48,432 B -> 48,640 alloc; 3 x 48,640 = 145,920 <= 150,528 (r0-proven).
// Alias lifetimes:
//   sLb over sXa          : old x dead after (a); rewritten by (e).
//   sRb_t over regB blk t : xh/xl(t) dead after pass-t fragment loads (barrier).
//   sS  over regB         : l/r dead after (c) reads (barrier in (c)).
__attribute__((amdgpu_flat_work_group_size(256, 256)))
__global__ void appnp_kernel(const float* __restrict__ x,
                  const float* __restrict__ og, const float* __restrict__ ob,
                  const float* __restrict__ lg, const float* __restrict__ lb,
                  const float* __restrict__ aw, const float* __restrict__ ab,
                  const float* __restrict__ psw, const float* __restrict__ psb,
                  const ushort_t* __restrict__ whi, const ushort_t* __restrict__ wlo,
                  const float* __restrict__ bcat,
                  float* __restrict__ out)
{
    __shared__ __align__(16) float smem[12108];
    float*    sXa  = smem;                         // [0,4488) 2x2244 f state x [sLb alias]
    ushort_t* sLb  = (ushort_t*)smem;              //   2x4488 ush l bf16 (ALIAS sXa)
    // region B [4488,8976): per-token blocks of 4488 ush:
    //   block t: xh rows0-15 [0,2176), xl rows0-15 [2176,4352), pad [4352,4488)
    //   overlay: sRb_t (17 rows x 264 ush = 4488)
    ushort_t* regBu = (ushort_t*)(smem + 4488);
    ushort_t* sRb   = regBu;                       // sRb + tau*4488 overlays block tau
    float*    sS    = smem + 4488;                 // 2x578 f scores (overlay after (c))
    ushort_t* stash = (ushort_t*)(smem + 8976);    // [8976,9248) row16 xh/xl: tau*272 + {0:h,136:l}
    ushort_t* sVb   = (ushort_t*)(smem + 9248);    // [9248,11560) 2x2312 ush V bf16
    float*    sK    = smem + 11560;                // 36
    float*    sLG   = smem + 11596;                // 128
    float*    sLBt  = smem + 11724;                // 128
    float*    sPW   = smem + 11852;                // 128
    float*    sAW   = smem + 11980;                // 128 -> total 12,108 f

    const int t = threadIdx.x;
    const int wave = t >> 6, lane = t & 63, l16 = lane & 15, quad = lane >> 4;
    const long long base = (long long)blockIdx.x * (2*TOKE);

    // uniform scalars (L2-resident s_load)
    const float abv  = ab[0];
    const float psbv = psb[0];

    // ---- stage small params ----
    if (t < 128){ sLG[t] = lg[t]; sLBt[t] = lb[t]; sPW[t] = psw[t]; sAW[t] = aw[t]; }

    // ---- load x for 2 tokens (1088 float4 groups, contiguous) ----
    for (int idx = t; idx < 1088; idx += 256){
        int r2 = idx >> 5, c = (idx & 31) << 2;
        int tau = (r2 >= NJ), r = r2 - NJ*tau;
        *(float4*)(sXa + tau*2244 + r*XS + c) = *(const float4*)(x + base + idx*4);
    }
    __syncthreads();

    // ---- outer LN -> sX in place; x0 copy -> out (global, read back in (e)) ----
    #pragma unroll
    for (int p = 0; p < 5; p++){
        int idx = t + (p << 8);
        if (p < 4 || t < 64){
            int r2 = idx >> 5, c = (idx & 31) << 2;
            int tau = (r2 >= NJ), r = r2 - NJ*tau;
            float* px = sXa + tau*2244 + r*XS + c;
            float4 v = *(float4*)px;
            float s = v.x + v.y + v.z + v.w;
            float q = v.x*v.x + v.y*v.y + v.z*v.z + v.w*v.w;
            #pragma unroll
            for (int m = 1; m <= 16; m <<= 1){ s += __shfl_xor(s, m); q += __shfl_xor(q, m); }
            float mu = s * (1.f/128.f);
            float rs = rsqrtf(q * (1.f/128.f) - mu*mu + 1e-5f);
            float4 g = *(const float4*)(og + c);
            float4 b = *(const float4*)(ob + c);
            float4 nv;
            nv.x = (v.x-mu)*rs*g.x + b.x;  nv.y = (v.y-mu)*rs*g.y + b.y;
            nv.z = (v.z-mu)*rs*g.z + b.z;  nv.w = (v.w-mu)*rs*g.w + b.w;
            *(float4*)px = nv;
            *(float4*)(out + base + idx*4) = nv;   // x0 kept in out until final store
        }
    }
    __syncthreads();

    for (int it = 0; it < 4; it++){
        // ---- (a) inner LN -> xh/xl bf16 hi/lo (RTNE split) + fused skip gate ----
        {
            #pragma unroll
            for (int p = 0; p < 5; p++){
                int idx = t + (p << 8);
                if (p < 4 || t < 64){
                    int r2 = idx >> 5, c = (idx & 31) << 2;
                    int tau = (r2 >= NJ), r = r2 - NJ*tau;
                    float4 v = *(const float4*)(sXa + tau*2244 + r*XS + c);
                    float s = v.x + v.y + v.z + v.w;
                    float q = v.x*v.x + v.y*v.y + v.z*v.z + v.w*v.w;
                    #pragma unroll
                    for (int m = 1; m <= 16; m <<= 1){ s += __shfl_xor(s, m); q += __shfl_xor(q, m); }
                    float mu = s * (1.f/128.f);
                    float rs = rsqrtf(q * (1.f/128.f) - mu*mu + 1e-5f);
                    float4 g = *(const float4*)(sLG + c);
                    float4 b = *(const float4*)(sLBt + c);
                    float n0 = (v.x-mu)*rs*g.x + b.x, n1 = (v.y-mu)*rs*g.y + b.y;
                    float n2 = (v.z-mu)*rs*g.z + b.z, n3 = (v.w-mu)*rs*g.w + b.w;
                    uint_t h0 = f2bf(n0), h1 = f2bf(n1), h2 = f2bf(n2), h3 = f2bf(n3);
                    uint2 ph; ph.x = h0 | (h1 << 16); ph.y = h2 | (h3 << 16);
                    uint_t e0 = f2bf(n0 - bf2f(h0)), e1 = f2bf(n1 - bf2f(h1));
                    uint_t e2 = f2bf(n2 - bf2f(h2)), e3 = f2bf(n3 - bf2f(h3));
                    uint2 pl; pl.x = e0 | (e1 << 16); pl.y = e2 | (e3 << 16);
                    if (r < 16){
                        ushort_t* xb = regBu + tau*4488;
                        *(uint2*)(xb + r*XBS + c) = ph;
                        *(uint2*)(xb + 2176 + r*XBS + c) = pl;
                    } else {
                        ushort_t* st = stash + tau*272;
                        *(uint2*)(st + c) = ph;
                        *(uint2*)(st + 136 + c) = pl;
                    }
                    float4 a = *(const float4*)(sAW + c);
                    float sp = n0*a.x + n1*a.y + n2*a.z + n3*a.w;
                    #pragma unroll
                    for (int m = 1; m <= 16; m <<= 1) sp += __shfl_xor(sp, m);
                    if ((t & 31) == 0) sK[tau*18 + r] = 1.f / (1.f + expf(-(sp + abv)));
                }
            }
        }
        __syncthreads();

        // ---- (b) three-pass MFMA GEMM: pass0=t0 rows0-15, pass1=t1 rows0-15, pass2=row16s ----
        {
            const int btau = l16 & 1;   // pass2: col parity -> token of row16
            #pragma unroll 1
            for (int pass = 0; pass < 3; pass++){
                short8 Bh[4], Bl[4];
                if (pass < 2){
                    const ushort_t* xb = regBu + pass*4488 + l16*XBS + quad*8;
                    #pragma unroll
                    for (int ks = 0; ks < 4; ks++){
                        Bh[ks] = *(const short8*)(xb + ks*32);
                        Bl[ks] = *(const short8*)(xb + 2176 + ks*32);
                    }
                    // all waves must fragment-load block 'pass' before its overlay writes
                    __syncthreads();
                } else {
                    const ushort_t* sb = stash + btau*272 + quad*8;
                    #pragma unroll
                    for (int ks = 0; ks < 4; ks++){
                        Bh[ks] = *(const short8*)(sb + ks*32);
                        Bl[ks] = *(const short8*)(sb + 136 + ks*32);
                    }
                }
                const int fbase = wave * 160;
                #pragma unroll 2
                for (int ft = 0; ft < 10; ft++){
                    int f0 = fbase + ft*16;
                    const ushort_t* ah = whi + (f0 + l16)*128 + quad*8;
                    const ushort_t* al = wlo + (f0 + l16)*128 + quad*8;
                    short8 Ah[4], Al[4];
                    #pragma unroll
                    for (int ks = 0; ks < 4; ks++){
                        Ah[ks] = *(const short8*)(ah + ks*32);
                        Al[ks] = *(const short8*)(al + ks*32);
                    }
                    float4 bb = *(const float4*)(bcat + f0 + quad*4);
                    f32x4 acc;
                    acc[0] = bb.x; acc[1] = bb.y; acc[2] = bb.z; acc[3] = bb.w;
                    #pragma unroll
                    for (int ks = 0; ks < 4; ks++){
                        acc = __builtin_amdgcn_mfma_f32_16x16x32_bf16(Ah[ks], Bh[ks], acc, 0, 0, 0);
                        acc = __builtin_amdgcn_mfma_f32_16x16x32_bf16(Ah[ks], Bl[ks], acc, 0, 0, 0);
                        acc = __builtin_amdgcn_mfma_f32_16x16x32_bf16(Al[ks], Bh[ks], acc, 0, 0, 0);
                    }
                    int fb = f0 + quad*4;
                    uint2 pk;
                    pk.x = f2bf(acc[0]) | (f2bf(acc[1]) << 16);
                    pk.y = f2bf(acc[2]) | (f2bf(acc[3]) << 16);
                    if (pass < 2){
                        if (f0 < 256)
                            *(uint2*)(sLb + pass*4488 + l16*LBS + fb) = pk;
                        else if (f0 < 512)
                            *(uint2*)(sRb + pass*4488 + l16*LBS + (fb-256)) = pk;
                        else
                            *(uint2*)(sVb + pass*2312 + l16*XBS + (fb-512)) = pk;
                    } else if (l16 < 2){
                        if (f0 < 256)
                            *(uint2*)(sLb + btau*4488 + 16*LBS + fb) = pk;
                        else if (f0 < 512)
                            *(uint2*)(sRb + btau*4488 + 16*LBS + (fb-256)) = pk;
                        else
                            *(uint2*)(sVb + btau*2312 + 16*XBS + (fb-512)) = pk;
                    }
                }
            }
        }
        __syncthreads();

        // ---- (c) attention scores: 2 tok x 2 head x 49 pairs = 196 tasks ----
        // Stage 1: read sLb/sRb into regs. Stage 2 (after barrier): write sS over region B.
        {
            float accv = 0.f; int sidx = 0;
            if (t < 196){
                int tau = (t >= 98); int th = t - 98*tau;
                int h = (th >= 49);  int p = th - 49*h;
                unsigned short pr = PAIR[p];
                int i = pr >> 8, j = pr & 255;
                const uint4* lp = (const uint4*)(sLb + tau*4488 + i*LBS + h*128);
                const uint4* rp = (const uint4*)(sRb + tau*4488 + j*LBS + h*128);
                float accA = 0.f, accB = 0.f;   // 2 chains to halve dep latency
                #pragma unroll
                for (int d = 0; d < 16; d++){
                    uint4 lu = lp[d], ru = rp[d];
                    float4 p0 = *(const float4*)(sPW + d*8);
                    float4 p1 = *(const float4*)(sPW + d*8 + 4);
                    accA += lrelu02(bflo(lu.x) + bflo(ru.x)) * p0.x;
                    accB += lrelu02(bfhi(lu.x) + bfhi(ru.x)) * p0.y;
                    accA += lrelu02(bflo(lu.y) + bflo(ru.y)) * p0.z;
                    accB += lrelu02(bfhi(lu.y) + bfhi(ru.y)) * p0.w;
                    accA += lrelu02(bflo(lu.z) + bflo(ru.z)) * p1.x;
                    accB += lrelu02(bfhi(lu.z) + bfhi(ru.z)) * p1.y;
                    accA += lrelu02(bflo(lu.w) + bflo(ru.w)) * p1.z;
                    accB += lrelu02(bfhi(lu.w) + bfhi(ru.w)) * p1.w;
                }
                accv = accA + accB + psbv;
                sidx = tau*578 + (h*NJ + i)*SS + j;
            }
            __syncthreads();   // drain all sLb/sRb reads before sS overlays region B
            if (t < 196) sS[sidx] = accv;
        }
        __syncthreads();

        // ---- (d) masked softmax: 2 tok x 34 rows, 2 lanes/row parity split ----
        if (t < 136){
            int rid = t >> 1, sub = t & 1;
            int tau = (rid >= 34); int r34 = rid - 34*tau;
            int h = (r34 >= NJ);   int i = r34 - NJ*h;
            float* sp = sS + tau*578 + (h*NJ + i)*SS;
            unsigned int m = ADJM[i];
            float mx = -1e30f;
            #pragma unroll
            for (int jj = 0; jj < 9; jj++){
                int j = 2*jj + sub;
                if (j < NJ && ((m >> j) & 1u)) mx = fmaxf(mx, sp[j]);
            }
            mx = fmaxf(mx, __shfl_xor(mx, 1));
            float pv[9]; float sum = 0.f;
            #pragma unroll
            for (int jj = 0; jj < 9; jj++){
                int j = 2*jj + sub;
                if (j < NJ && ((m >> j) & 1u)){ pv[jj] = expf(sp[j] - mx); sum += pv[jj]; }
                else pv[jj] = 0.f;
            }
            sum += __shfl_xor(sum, 1);
            float inv = 1.f / sum;
            #pragma unroll
            for (int jj = 0; jj < 9; jj++){
                int j = 2*jj + sub;
                if (j < NJ) sp[j] = pv[jj]*inv;
            }
        }
        __syncthreads();

        // ---- (e) PV (bf16 V) + gelu + blend (x0 from out) -> new x in sX ----
        #pragma unroll
        for (int p = 0; p < 5; p++){
            int idx = t + (p << 8);
            if (p < 4 || t < 64){
                int r2 = idx >> 5, cg = idx & 31;
                int tau = (r2 >= NJ), r = r2 - NJ*tau;
                int c = cg << 2, h = cg >> 4;
                float4 x0v = *(const float4*)(out + base + idx*4);   // issue early; L3-hot
                const float* sp = sS + tau*578 + (h*NJ + r)*SS;
                const ushort_t* vp = sVb + tau*2312 + c;
                float a0 = 0.f, a1 = 0.f, a2 = 0.f, a3 = 0.f;
                #pragma unroll
                for (int j = 0; j < NJ; j++){
                    float pj = sp[j];
                    uint2 vv = *(const uint2*)(vp + j*XBS);
                    a0 += pj*bflo(vv.x); a1 += pj*bfhi(vv.x);
                    a2 += pj*bflo(vv.y); a3 += pj*bfhi(vv.y);
                }
                a0 = gelu_exact(a0); a1 = gelu_exact(a1); a2 = gelu_exact(a2); a3 = gelu_exact(a3);
                float sk = sK[tau*18 + r];
                float4 nx;
                nx.x = (1.f-sk)*a0 + sk*x0v.x;  nx.y = (1.f-sk)*a1 + sk*x0v.y;
                nx.z = (1.f-sk)*a2 + sk*x0v.z;  nx.w = (1.f-sk)*a3 + sk*x0v.w;
                *(float4*)(sXa + tau*2244 + r*XS + c) = nx;
            }
        }
        __syncthreads();
    }

    // ---- store (overwrites the x0 copy) ----
    for (int idx = t; idx < 1088; idx += 256){
        int r2 = idx >> 5, c = (idx & 31) << 2;
        int tau = (r2 >= NJ), r = r2 - NJ*tau;
        *(float4*)(out + base + idx*4) = *(const float4*)(sXa + tau*2244 + r*XS + c);
    }
}

extern "C" void kernel_launch(void* const* d_in, const int* in_sizes, int n_in,
                              void* d_out, int out_size, void* d_ws, size_t ws_size,
                              hipStream_t stream) {
    const float* x   = (const float*)d_in[0];
    const float* og  = (const float*)d_in[1];
    const float* ob  = (const float*)d_in[2];
    const float* lg  = (const float*)d_in[3];
    const float* lb  = (const float*)d_in[4];
    const float* aw  = (const float*)d_in[5];
    const float* ab  = (const float*)d_in[6];
    const float* w1  = (const float*)d_in[7];
    const float* b1  = (const float*)d_in[8];
    const float* w2  = (const float*)d_in[9];
    const float* b2  = (const float*)d_in[10];
    const float* psw = (const float*)d_in[11];
    const float* psb = (const float*)d_in[12];
    const float* vw  = (const float*)d_in[13];
    const float* vb  = (const float*)d_in[14];
    float* out = (float*)d_out;

    // workspace: whi (640*128 bf16) + wlo (640*128 bf16) + bcat (640 f32) = 330,240 B
    ushort_t* whi = (ushort_t*)d_ws;
    ushort_t* wlo = whi + 640*128;
    float* bcat = (float*)(wlo + 640*128);

    prep_kernel<<<dim3(320), dim3(256), 0, stream>>>(w1, b1, w2, b2, vw, vb, whi, wlo, bcat);

    int BT = in_sizes[0] / TOKE;   // 3888 tokens
    appnp_kernel<<<dim3(BT/2), dim3(256), 0, stream>>>(
        x, og, ob, lg, lb, aw, ab, psw, psb, whi, wlo, bcat, out);
}

// Round 9
// 446.827 us; speedup vs baseline: 2.4591x; 2.4591x over previous
//
#include <hip/hip_runtime.h>
#include <math.h>

#define NJ 17
#define XS 132      // fp32 row stride for sX (floats)
#define LBS 264     // ushort row stride for sLb/sRb
#define XBS 136     // ushort row stride for sXh/sXl/sVb (16B-aligned rows)
#define SS 17       // score row stride (floats)
#define TOKE (NJ*128)

typedef unsigned short ushort_t;
typedef unsigned int uint_t;
typedef __attribute__((ext_vector_type(8))) short short8;
typedef __attribute__((ext_vector_type(4))) float f32x4;

// adjacency bitmasks (both dirs + diag)
__device__ __constant__ unsigned int ADJM[NJ] = {
    0x93u, 0x7u, 0xEu, 0xCu, 0x31u, 0x70u, 0x60u,
    0x181u, 0x4B80u, 0x700u, 0x600u, 0x1900u, 0x3800u, 0x3000u,
    0xC100u, 0x1C000u, 0x18000u
};
// dense list of the 49 adjacent (i,j) pairs, packed (i<<8)|j
__device__ __constant__ unsigned short PAIR[49] = {
    0x0000,0x0001,0x0004,0x0007, 0x0100,0x0101,0x0102, 0x0201,0x0202,0x0203,
    0x0302,0x0303, 0x0400,0x0404,0x0405, 0x0504,0x0505,0x0506, 0x0605,0x0606,
    0x0700,0x0707,0x0708, 0x0807,0x0808,0x0809,0x080B,0x080E, 0x0908,0x0909,0x090A,
    0x0A09,0x0A0A, 0x0B08,0x0B0B,0x0B0C, 0x0C0B,0x0C0C,0x0C0D, 0x0D0C,0x0D0D,
    0x0E08,0x0E0E,0x0E0F, 0x0F0E,0x0F0F,0x0F10, 0x100F,0x1010
};

__device__ __forceinline__ uint_t f2bf(float v){
    uint_t u = __float_as_uint(v);
    return (u + 0x7FFFu + ((u >> 16) & 1u)) >> 16;
}
__device__ __forceinline__ float bf2f(uint_t h){ return __uint_as_float(h << 16); }
__device__ __forceinline__ float bflo(uint_t u){ return __uint_as_float(u << 16); }
__device__ __forceinline__ float bfhi(uint_t u){ return __uint_as_float(u & 0xFFFF0000u); }
__device__ __forceinline__ float lrelu02(float u){ return fmaxf(u, 0.f) + 0.2f*fminf(u, 0.f); }
__device__ __forceinline__ float gelu_exact(float x){ return 0.5f*x*(1.f + erff(x*0.70710678118654752f)); }

// prep: WT[f][k] bf16 hi/lo (f: 0..255 w1-col, 256..511 w2-col, 512..639 vw-col) + bcat
// (wlo kept for layout compatibility; r9 kernel no longer reads it)
__global__ void prep_kernel(const float* __restrict__ w1, const float* __restrict__ b1,
                            const float* __restrict__ w2, const float* __restrict__ b2,
                            const float* __restrict__ vw, const float* __restrict__ vb,
                            ushort_t* __restrict__ whi, ushort_t* __restrict__ wlo,
                            float* __restrict__ bcat){
    int gid = blockIdx.x*256 + threadIdx.x;
    if (gid < 640*128){
        int f = gid >> 7, k = gid & 127;
        float v;
        if (f < 256)      v = w1[k*256 + f];
        else if (f < 512) v = w2[k*256 + (f-256)];
        else              v = vw[k*128 + (f-512)];
        uint_t h = f2bf(v);
        whi[gid] = (ushort_t)h;
        wlo[gid] = (ushort_t)f2bf(v - bf2f(h));
    }
    if (gid < 640){
        float b;
        if (gid < 256)      b = b1[gid];
        else if (gid < 512) b = b2[gid-256];
        else                b = vb[gid-512];
        bcat[gid] = b;
    }
}

// r9: r7 structure with two changes:
//   (1) drop the Al*Bh MFMA term (W-residual): -33% MFMAs, -50% A-stream, -16 VGPR.
//       x stays hi/lo split (Ah*Bh + Ah*Bl); W is bf16-hi only. Numerics: W-residual
//       contributes ~2e-3 to scores/V, far under the 0.0156 output floor.
//   (2) x0 kept in `out` (r8-proven clean): -20 VGPR.
// Everything else byte-identical to r7 (497 us, absmax 0.015625).
// LDS 11,972 f = 47,888 B -> 48,128 alloc (3x = 144,384, fits r0-proven envelope).
// Alias lifetimes:
//   sLb over sXa      : old x dead after (a); rewritten by (e).
//   sRb over sXh/sXl  : xn hi/lo dead after (b)'s fragment loads (barrier in (b)).
//   sS  over sRb      : l/r dead after (c)'s reads (barrier in (c)).
__attribute__((amdgpu_flat_work_group_size(256, 256)))
__global__ void appnp_kernel(const float* __restrict__ x,
                  const float* __restrict__ og, const float* __restrict__ ob,
                  const float* __restrict__ lg, const float* __restrict__ lb,
                  const float* __restrict__ aw, const float* __restrict__ ab,
                  const float* __restrict__ psw, const float* __restrict__ psb,
                  const ushort_t* __restrict__ whi, const ushort_t* __restrict__ wlo,
                  const float* __restrict__ bcat,
                  float* __restrict__ out)
{
    __shared__ __align__(16) float smem[11972];
    float*    sXa  = smem;                            // [0,4488)  2x2244 f state x [sLb alias]
    ushort_t* sLb  = (ushort_t*)smem;                 //   2x4488 ush l bf16 (ALIAS sXa)
    ushort_t* sXh  = (ushort_t*)(smem + 4488);        // region B: 2x2312 ush xn bf16-hi
    ushort_t* sXl  = (ushort_t*)(smem + 4488) + 4624; //           2x2312 ush xn bf16-lo
    ushort_t* sRb  = (ushort_t*)(smem + 4488);        //   2x4488 ush r bf16 (ALIAS sXh/sXl)
    float*    sS   = smem + 4488;                     //   2x578 f scores (ALIAS sRb, after (c))
    ushort_t* sVb  = (ushort_t*)(smem + 9112);        // [9112,11424) 2x2312 ush V bf16
    float*    sK   = smem + 11424;                    // 2 x 18
    float*    sLG  = smem + 11460;                    // 128
    float*    sLBt = smem + 11588;                    // 128
    float*    sPW  = smem + 11716;                    // 128
    float*    sAW  = smem + 11844;                    // 128  -> total 11,972 f = 47,888 B

    const int t = threadIdx.x;
    const int wave = t >> 6, lane = t & 63, l16 = lane & 15, quad = lane >> 4;
    const long long base = (long long)blockIdx.x * (2*TOKE);

    // uniform scalars (L2-resident s_load)
    const float abv  = ab[0];
    const float psbv = psb[0];

    // ---- stage small params ----
    if (t < 128){ sLG[t] = lg[t]; sLBt[t] = lb[t]; sPW[t] = psw[t]; sAW[t] = aw[t]; }

    // ---- load x for 2 tokens (1088 float4 groups, contiguous) ----
    for (int idx = t; idx < 1088; idx += 256){
        int r2 = idx >> 5, c = (idx & 31) << 2;
        int tau = (r2 >= NJ), r = r2 - NJ*tau;
        *(float4*)(sXa + tau*2244 + r*XS + c) = *(const float4*)(x + base + idx*4);
    }
    __syncthreads();

    // ---- outer LN -> sX in place; x0 copy -> out (global, read back in (e)) ----
    #pragma unroll
    for (int p = 0; p < 5; p++){
        int idx = t + (p << 8);
        if (p < 4 || t < 64){
            int r2 = idx >> 5, c = (idx & 31) << 2;
            int tau = (r2 >= NJ), r = r2 - NJ*tau;
            float* px = sXa + tau*2244 + r*XS + c;
            float4 v = *(float4*)px;
            float s = v.x + v.y + v.z + v.w;
            float q = v.x*v.x + v.y*v.y + v.z*v.z + v.w*v.w;
            #pragma unroll
            for (int m = 1; m <= 16; m <<= 1){ s += __shfl_xor(s, m); q += __shfl_xor(q, m); }
            float mu = s * (1.f/128.f);
            float rs = rsqrtf(q * (1.f/128.f) - mu*mu + 1e-5f);
            float4 g = *(const float4*)(og + c);
            float4 b = *(const float4*)(ob + c);
            float4 nv;
            nv.x = (v.x-mu)*rs*g.x + b.x;  nv.y = (v.y-mu)*rs*g.y + b.y;
            nv.z = (v.z-mu)*rs*g.z + b.z;  nv.w = (v.w-mu)*rs*g.w + b.w;
            *(float4*)px = nv;
            *(float4*)(out + base + idx*4) = nv;   // x0 parked in out until final store
        }
    }
    __syncthreads();

    for (int it = 0; it < 4; it++){
        // ---- (a) inner LN -> sXh/sXl bf16 hi/lo (RTNE split) + fused skip gate ----
        {
            #pragma unroll
            for (int p = 0; p < 5; p++){
                int idx = t + (p << 8);
                if (p < 4 || t < 64){
                    int r2 = idx >> 5, c = (idx & 31) << 2;
                    int tau = (r2 >= NJ), r = r2 - NJ*tau;
                    float4 v = *(const float4*)(sXa + tau*2244 + r*XS + c);
                    float s = v.x + v.y + v.z + v.w;
                    float q = v.x*v.x + v.y*v.y + v.z*v.z + v.w*v.w;
                    #pragma unroll
                    for (int m = 1; m <= 16; m <<= 1){ s += __shfl_xor(s, m); q += __shfl_xor(q, m); }
                    float mu = s * (1.f/128.f);
                    float rs = rsqrtf(q * (1.f/128.f) - mu*mu + 1e-5f);
                    float4 g = *(const float4*)(sLG + c);
                    float4 b = *(const float4*)(sLBt + c);
                    float n0 = (v.x-mu)*rs*g.x + b.x, n1 = (v.y-mu)*rs*g.y + b.y;
                    float n2 = (v.z-mu)*rs*g.z + b.z, n3 = (v.w-mu)*rs*g.w + b.w;
                    uint_t h0 = f2bf(n0), h1 = f2bf(n1), h2 = f2bf(n2), h3 = f2bf(n3);
                    uint2 ph; ph.x = h0 | (h1 << 16); ph.y = h2 | (h3 << 16);
                    uint_t e0 = f2bf(n0 - bf2f(h0)), e1 = f2bf(n1 - bf2f(h1));
                    uint_t e2 = f2bf(n2 - bf2f(h2)), e3 = f2bf(n3 - bf2f(h3));
                    uint2 pl; pl.x = e0 | (e1 << 16); pl.y = e2 | (e3 << 16);
                    *(uint2*)(sXh + tau*2312 + r*XBS + c) = ph;
                    *(uint2*)(sXl + tau*2312 + r*XBS + c) = pl;
                    float4 a = *(const float4*)(sAW + c);
                    float sp = n0*a.x + n1*a.y + n2*a.z + n3*a.w;
                    #pragma unroll
                    for (int m = 1; m <= 16; m <<= 1) sp += __shfl_xor(sp, m);
                    if ((t & 31) == 0) sK[tau*18 + r] = 1.f / (1.f + expf(-(sp + abv)));
                }
            }
        }
        __syncthreads();

        // ---- (b) MFMA GEMM (W bf16-hi only): B0/B1 = tokens' rows 0..15; B2 = rows 16 ----
        {
            short8 B0h[4], B0l[4], B1h[4], B1l[4], B2h[4], B2l[4];
            const int fo = l16*XBS + quad*8;
            #pragma unroll
            for (int ks = 0; ks < 4; ks++){
                B0h[ks] = *(const short8*)(sXh + fo + ks*32);
                B0l[ks] = *(const short8*)(sXl + fo + ks*32);
                B1h[ks] = *(const short8*)(sXh + 2312 + fo + ks*32);
                B1l[ks] = *(const short8*)(sXl + 2312 + fo + ks*32);
            }
            const int btau = l16 & 1;   // col 0 -> t0 row16, col 1 -> t1 row16 (others dup, unused)
            const int f16o = btau*2312 + 16*XBS + quad*8;
            #pragma unroll
            for (int ks = 0; ks < 4; ks++){
                B2h[ks] = *(const short8*)(sXh + f16o + ks*32);
                B2l[ks] = *(const short8*)(sXl + f16o + ks*32);
            }
            // sXh/sXl now dead; sRb aliases them -> all waves must pass here before writes
            __syncthreads();
            const int fbase = wave * 160;
            #pragma unroll 2
            for (int ft = 0; ft < 10; ft++){
                int f0 = fbase + ft*16;
                const ushort_t* ah = whi + (f0 + l16)*128 + quad*8;
                short8 Ah[4];
                #pragma unroll
                for (int ks = 0; ks < 4; ks++)
                    Ah[ks] = *(const short8*)(ah + ks*32);
                float4 bb = *(const float4*)(bcat + f0 + quad*4);
                f32x4 a0, a1, a2;
                a0[0] = bb.x; a0[1] = bb.y; a0[2] = bb.z; a0[3] = bb.w;
                a1 = a0; a2 = a0;
                #pragma unroll
                for (int ks = 0; ks < 4; ks++){
                    a0 = __builtin_amdgcn_mfma_f32_16x16x32_bf16(Ah[ks], B0h[ks], a0, 0, 0, 0);
                    a1 = __builtin_amdgcn_mfma_f32_16x16x32_bf16(Ah[ks], B1h[ks], a1, 0, 0, 0);
                    a2 = __builtin_amdgcn_mfma_f32_16x16x32_bf16(Ah[ks], B2h[ks], a2, 0, 0, 0);
                    a0 = __builtin_amdgcn_mfma_f32_16x16x32_bf16(Ah[ks], B0l[ks], a0, 0, 0, 0);
                    a1 = __builtin_amdgcn_mfma_f32_16x16x32_bf16(Ah[ks], B1l[ks], a1, 0, 0, 0);
                    a2 = __builtin_amdgcn_mfma_f32_16x16x32_bf16(Ah[ks], B2l[ks], a2, 0, 0, 0);
                }
                int fb = f0 + quad*4;
                if (f0 < 512){
                    ushort_t* bse; int col;
                    if (f0 < 256){ bse = sLb; col = fb; } else { bse = sRb; col = fb - 256; }
                    uint2 p0;
                    p0.x = f2bf(a0[0]) | (f2bf(a0[1]) << 16);
                    p0.y = f2bf(a0[2]) | (f2bf(a0[3]) << 16);
                    *(uint2*)(bse + l16*LBS + col) = p0;
                    uint2 p1;
                    p1.x = f2bf(a1[0]) | (f2bf(a1[1]) << 16);
                    p1.y = f2bf(a1[2]) | (f2bf(a1[3]) << 16);
                    *(uint2*)(bse + 4488 + l16*LBS + col) = p1;
                    if (l16 < 2){
                        uint2 p2;
                        p2.x = f2bf(a2[0]) | (f2bf(a2[1]) << 16);
                        p2.y = f2bf(a2[2]) | (f2bf(a2[3]) << 16);
                        *(uint2*)(bse + btau*4488 + 16*LBS + col) = p2;
                    }
                } else {
                    int col = fb - 512;
                    uint2 q0;
                    q0.x = f2bf(a0[0]) | (f2bf(a0[1]) << 16);
                    q0.y = f2bf(a0[2]) | (f2bf(a0[3]) << 16);
                    *(uint2*)(sVb + l16*XBS + col) = q0;
                    uint2 q1;
                    q1.x = f2bf(a1[0]) | (f2bf(a1[1]) << 16);
                    q1.y = f2bf(a1[2]) | (f2bf(a1[3]) << 16);
                    *(uint2*)(sVb + 2312 + l16*XBS + col) = q1;
                    if (l16 < 2){
                        uint2 q2;
                        q2.x = f2bf(a2[0]) | (f2bf(a2[1]) << 16);
                        q2.y = f2bf(a2[2]) | (f2bf(a2[3]) << 16);
                        *(uint2*)(sVb + btau*2312 + 16*XBS + col) = q2;
                    }
                }
            }
        }
        __syncthreads();

        // ---- (c) attention scores: 2 tok x 2 head x 49 pairs = 196 tasks ----
        // Stage 1: read sLb/sRb into regs. Stage 2 (after barrier): write sS over sRb.
        {
            float accv = 0.f; int sidx = 0;
            if (t < 196){
                int tau = (t >= 98); int th = t - 98*tau;
                int h = (th >= 49);  int p = th - 49*h;
                unsigned short pr = PAIR[p];
                int i = pr >> 8, j = pr & 255;
                const uint4* lp = (const uint4*)(sLb + tau*4488 + i*LBS + h*128);
                const uint4* rp = (const uint4*)(sRb + tau*4488 + j*LBS + h*128);
                float accA = 0.f, accB = 0.f;   // 2 chains to halve dep latency
                #pragma unroll
                for (int d = 0; d < 16; d++){
                    uint4 lu = lp[d], ru = rp[d];
                    float4 p0 = *(const float4*)(sPW + d*8);
                    float4 p1 = *(const float4*)(sPW + d*8 + 4);
                    accA += lrelu02(bflo(lu.x) + bflo(ru.x)) * p0.x;
                    accB += lrelu02(bfhi(lu.x) + bfhi(ru.x)) * p0.y;
                    accA += lrelu02(bflo(lu.y) + bflo(ru.y)) * p0.z;
                    accB += lrelu02(bfhi(lu.y) + bfhi(ru.y)) * p0.w;
                    accA += lrelu02(bflo(lu.z) + bflo(ru.z)) * p1.x;
                    accB += lrelu02(bfhi(lu.z) + bfhi(ru.z)) * p1.y;
                    accA += lrelu02(bflo(lu.w) + bflo(ru.w)) * p1.z;
                    accB += lrelu02(bfhi(lu.w) + bfhi(ru.w)) * p1.w;
                }
                accv = accA + accB + psbv;
                sidx = tau*578 + (h*NJ + i)*SS + j;
            }
            __syncthreads();   // drain all sLb/sRb reads before sS overlays sRb
            if (t < 196) sS[sidx] = accv;
        }
        __syncthreads();

        // ---- (d) masked softmax: 2 tok x 34 rows, 2 lanes/row parity split ----
        if (t < 136){
            int rid = t >> 1, sub = t & 1;
            int tau = (rid >= 34); int r34 = rid - 34*tau;
            int h = (r34 >= NJ);   int i = r34 - NJ*h;
            float* sp = sS + tau*578 + (h*NJ + i)*SS;
            unsigned int m = ADJM[i];
            float mx = -1e30f;
            #pragma unroll
            for (int jj = 0; jj < 9; jj++){
                int j = 2*jj + sub;
                if (j < NJ && ((m >> j) & 1u)) mx = fmaxf(mx, sp[j]);
            }
            mx = fmaxf(mx, __shfl_xor(mx, 1));
            float pv[9]; float sum = 0.f;
            #pragma unroll
            for (int jj = 0; jj < 9; jj++){
                int j = 2*jj + sub;
                if (j < NJ && ((m >> j) & 1u)){ pv[jj] = expf(sp[j] - mx); sum += pv[jj]; }
                else pv[jj] = 0.f;
            }
            sum += __shfl_xor(sum, 1);
            float inv = 1.f / sum;
            #pragma unroll
            for (int jj = 0; jj < 9; jj++){
                int j = 2*jj + sub;
                if (j < NJ) sp[j] = pv[jj]*inv;
            }
        }
        __syncthreads();

        // ---- (e) PV (bf16 V) + gelu + blend (x0 from out) -> new x in sX ----
        #pragma unroll
        for (int p = 0; p < 5; p++){
            int idx = t + (p << 8);
            if (p < 4 || t < 64){
                int r2 = idx >> 5, cg = idx & 31;
                int tau = (r2 >= NJ), r = r2 - NJ*tau;
                int c = cg << 2, h = cg >> 4;
                float4 x0v = *(const float4*)(out + base + idx*4);   // issue early; L2-hot
                const float* sp = sS + tau*578 + (h*NJ + r)*SS;
                const ushort_t* vp = sVb + tau*2312 + c;
                float a0 = 0.f, a1 = 0.f, a2 = 0.f, a3 = 0.f;
                #pragma unroll
                for (int j = 0; j < NJ; j++){
                    float pj = sp[j];
                    uint2 vv = *(const uint2*)(vp + j*XBS);
                    a0 += pj*bflo(vv.x); a1 += pj*bfhi(vv.x);
                    a2 += pj*bflo(vv.y); a3 += pj*bfhi(vv.y);
                }
                a0 = gelu_exact(a0); a1 = gelu_exact(a1); a2 = gelu_exact(a2); a3 = gelu_exact(a3);
                float sk = sK[tau*18 + r];
                float4 nx;
                nx.x = (1.f-sk)*a0 + sk*x0v.x;  nx.y = (1.f-sk)*a1 + sk*x0v.y;
                nx.z = (1.f-sk)*a2 + sk*x0v.z;  nx.w = (1.f-sk)*a3 + sk*x0v.w;
                *(float4*)(sXa + tau*2244 + r*XS + c) = nx;
            }
        }
        __syncthreads();
    }

    // ---- store (overwrites the x0 copy) ----
    for (int idx = t; idx < 1088; idx += 256){
        int r2 = idx >> 5, c = (idx & 31) << 2;
        int tau = (r2 >= NJ), r = r2 - NJ*tau;
        *(float4*)(out + base + idx*4) = *(const float4*)(sXa + tau*2244 + r*XS + c);
    }
}

extern "C" void kernel_launch(void* const* d_in, const int* in_sizes, int n_in,
                              void* d_out, int out_size, void* d_ws, size_t ws_size,
                              hipStream_t stream) {
    const float* x   = (const float*)d_in[0];
    const float* og  = (const float*)d_in[1];
    const float* ob  = (const float*)d_in[2];
    const float* lg  = (const float*)d_in[3];
    const float* lb  = (const float*)d_in[4];
    const float* aw  = (const float*)d_in[5];
    const float* ab  = (const float*)d_in[6];
    const float* w1  = (const float*)d_in[7];
    const float* b1  = (const float*)d_in[8];
    const float* w2  = (const float*)d_in[9];
    const float* b2  = (const float*)d_in[10];
    const float* psw = (const float*)d_in[11];
    const float* psb = (const float*)d_in[12];
    const float* vw  = (const float*)d_in[13];
    const float* vb  = (const float*)d_in[14];
    float* out = (float*)d_out;

    // workspace: whi (640*128 bf16) + wlo (640*128 bf16) + bcat (640 f32) = 330,240 B
    ushort_t* whi = (ushort_t*)d_ws;
    ushort_t* wlo = whi + 640*128;
    float* bcat = (float*)(wlo + 640*128);

    prep_kernel<<<dim3(320), dim3(256), 0, stream>>>(w1, b1, w2, b2, vw, vb, whi, wlo, bcat);

    int BT = in_sizes[0] / TOKE;   // 3888 tokens
    appnp_kernel<<<dim3(BT/2), dim3(256), 0, stream>>>(
        x, og, ob, lg, lb, aw, ab, psw, psb, whi, wlo, bcat, out);
}

// Round 10
// 426.694 us; speedup vs baseline: 2.5751x; 1.0472x over previous
//
#include <hip/hip_runtime.h>
#include <math.h>

#define NJ 17
#define XS 132      // fp32 row stride for sX (floats)
#define LBS 264     // ushort row stride for sLb/sRb
#define XBS 136     // ushort row stride for sXh/sVb (16B-aligned rows)
#define SS 17       // score row stride (floats)
#define TOKE (NJ*128)

typedef unsigned short ushort_t;
typedef unsigned int uint_t;
typedef __attribute__((ext_vector_type(8))) short short8;
typedef __attribute__((ext_vector_type(4))) float f32x4;

// adjacency bitmasks (both dirs + diag)
__device__ __constant__ unsigned int ADJM[NJ] = {
    0x93u, 0x7u, 0xEu, 0xCu, 0x31u, 0x70u, 0x60u,
    0x181u, 0x4B80u, 0x700u, 0x600u, 0x1900u, 0x3800u, 0x3000u,
    0xC100u, 0x1C000u, 0x18000u
};
// dense list of the 49 adjacent (i,j) pairs, packed (i<<8)|j
__device__ __constant__ unsigned short PAIR[49] = {
    0x0000,0x0001,0x0004,0x0007, 0x0100,0x0101,0x0102, 0x0201,0x0202,0x0203,
    0x0302,0x0303, 0x0400,0x0404,0x0405, 0x0504,0x0505,0x0506, 0x0605,0x0606,
    0x0700,0x0707,0x0708, 0x0807,0x0808,0x0809,0x080B,0x080E, 0x0908,0x0909,0x090A,
    0x0A09,0x0A0A, 0x0B08,0x0B0B,0x0B0C, 0x0C0B,0x0C0C,0x0C0D, 0x0D0C,0x0D0D,
    0x0E08,0x0E0E,0x0E0F, 0x0F0E,0x0F0F,0x0F10, 0x100F,0x1010
};

__device__ __forceinline__ uint_t f2bf(float v){
    uint_t u = __float_as_uint(v);
    return (u + 0x7FFFu + ((u >> 16) & 1u)) >> 16;
}
__device__ __forceinline__ float bf2f(uint_t h){ return __uint_as_float(h << 16); }
__device__ __forceinline__ float bflo(uint_t u){ return __uint_as_float(u << 16); }
__device__ __forceinline__ float bfhi(uint_t u){ return __uint_as_float(u & 0xFFFF0000u); }
__device__ __forceinline__ float lrelu02(float u){ return fmaxf(u, 0.f) + 0.2f*fminf(u, 0.f); }
__device__ __forceinline__ float gelu_exact(float x){ return 0.5f*x*(1.f + erff(x*0.70710678118654752f)); }

// prep: WT[f][k] bf16-hi (f: 0..255 w1-col, 256..511 w2-col, 512..639 vw-col) + bcat
// (wlo kept in workspace layout for compatibility; unused since r9)
__global__ void prep_kernel(const float* __restrict__ w1, const float* __restrict__ b1,
                            const float* __restrict__ w2, const float* __restrict__ b2,
                            const float* __restrict__ vw, const float* __restrict__ vb,
                            ushort_t* __restrict__ whi, ushort_t* __restrict__ wlo,
                            float* __restrict__ bcat){
    int gid = blockIdx.x*256 + threadIdx.x;
    if (gid < 640*128){
        int f = gid >> 7, k = gid & 127;
        float v;
        if (f < 256)      v = w1[k*256 + f];
        else if (f < 512) v = w2[k*256 + (f-256)];
        else              v = vw[k*128 + (f-512)];
        uint_t h = f2bf(v);
        whi[gid] = (ushort_t)h;
        wlo[gid] = (ushort_t)f2bf(v - bf2f(h));
    }
    if (gid < 640){
        float b;
        if (gid < 256)      b = b1[gid];
        else if (gid < 512) b = b2[gid-256];
        else                b = vb[gid-512];
        bcat[gid] = b;
    }
}

// r10: r9 with the x-residual MFMA term (Ah*Bl) dropped -> pure bf16xbf16 GEMM.
//   - B-lo fragments gone: -48 VGPR (target <=85 -> 3 waves/SIMD by the r0..r9
//     occupancy model waves/SIMD = floor(~256/VGPR)).
//   - (b) MFMAs halve (240->120/wave/iter); (a) loses residual compute+store.
//   - Numerics: x-lo term ~ W_hi*2^-9*x, same magnitude as the W-lo term dropped
//     in r9 (+0.008 absmax); predict absmax ~0.03-0.045 < 0.076 threshold.
// Everything else byte-identical to r9 (446.8 us, absmax 0.0234).
// LDS 11,972 f = 47,888 B -> 48,128 alloc (3x = 144,384, r0-proven envelope).
// Alias lifetimes:
//   sLb over sXa      : old x dead after (a); rewritten by (e).
//   sRb over sXh+pad  : xn-hi dead after (b)'s fragment loads (barrier in (b)).
//   sS  over sRb      : l/r dead after (c)'s reads (barrier in (c)).
__attribute__((amdgpu_flat_work_group_size(256, 256)))
__global__ void appnp_kernel(const float* __restrict__ x,
                  const float* __restrict__ og, const float* __restrict__ ob,
                  const float* __restrict__ lg, const float* __restrict__ lb,
                  const float* __restrict__ aw, const float* __restrict__ ab,
                  const float* __restrict__ psw, const float* __restrict__ psb,
                  const ushort_t* __restrict__ whi, const ushort_t* __restrict__ wlo,
                  const float* __restrict__ bcat,
                  float* __restrict__ out)
{
    __shared__ __align__(16) float smem[11972];
    float*    sXa  = smem;                            // [0,4488)  2x2244 f state x [sLb alias]
    ushort_t* sLb  = (ushort_t*)smem;                 //   2x4488 ush l bf16 (ALIAS sXa)
    ushort_t* sXh  = (ushort_t*)(smem + 4488);        // region B: 2x2312 ush xn bf16-hi
    ushort_t* sRb  = (ushort_t*)(smem + 4488);        //   2x4488 ush r bf16 (ALIAS sXh+pad)
    float*    sS   = smem + 4488;                     //   2x578 f scores (ALIAS sRb, after (c))
    ushort_t* sVb  = (ushort_t*)(smem + 9112);        // [9112,11424) 2x2312 ush V bf16
    float*    sK   = smem + 11424;                    // 2 x 18
    float*    sLG  = smem + 11460;                    // 128
    float*    sLBt = smem + 11588;                    // 128
    float*    sPW  = smem + 11716;                    // 128
    float*    sAW  = smem + 11844;                    // 128  -> total 11,972 f = 47,888 B

    const int t = threadIdx.x;
    const int wave = t >> 6, lane = t & 63, l16 = lane & 15, quad = lane >> 4;
    const long long base = (long long)blockIdx.x * (2*TOKE);

    // uniform scalars (L2-resident s_load)
    const float abv  = ab[0];
    const float psbv = psb[0];

    // ---- stage small params ----
    if (t < 128){ sLG[t] = lg[t]; sLBt[t] = lb[t]; sPW[t] = psw[t]; sAW[t] = aw[t]; }

    // ---- load x for 2 tokens (1088 float4 groups, contiguous) ----
    for (int idx = t; idx < 1088; idx += 256){
        int r2 = idx >> 5, c = (idx & 31) << 2;
        int tau = (r2 >= NJ), r = r2 - NJ*tau;
        *(float4*)(sXa + tau*2244 + r*XS + c) = *(const float4*)(x + base + idx*4);
    }
    __syncthreads();

    // ---- outer LN -> sX in place; x0 copy -> out (global, read back in (e)) ----
    #pragma unroll
    for (int p = 0; p < 5; p++){
        int idx = t + (p << 8);
        if (p < 4 || t < 64){
            int r2 = idx >> 5, c = (idx & 31) << 2;
            int tau = (r2 >= NJ), r = r2 - NJ*tau;
            float* px = sXa + tau*2244 + r*XS + c;
            float4 v = *(float4*)px;
            float s = v.x + v.y + v.z + v.w;
            float q = v.x*v.x + v.y*v.y + v.z*v.z + v.w*v.w;
            #pragma unroll
            for (int m = 1; m <= 16; m <<= 1){ s += __shfl_xor(s, m); q += __shfl_xor(q, m); }
            float mu = s * (1.f/128.f);
            float rs = rsqrtf(q * (1.f/128.f) - mu*mu + 1e-5f);
            float4 g = *(const float4*)(og + c);
            float4 b = *(const float4*)(ob + c);
            float4 nv;
            nv.x = (v.x-mu)*rs*g.x + b.x;  nv.y = (v.y-mu)*rs*g.y + b.y;
            nv.z = (v.z-mu)*rs*g.z + b.z;  nv.w = (v.w-mu)*rs*g.w + b.w;
            *(float4*)px = nv;
            *(float4*)(out + base + idx*4) = nv;   // x0 parked in out until final store
        }
    }
    __syncthreads();

    for (int it = 0; it < 4; it++){
        // ---- (a) inner LN -> sXh bf16 (RTNE) + fused skip gate ----
        {
            #pragma unroll
            for (int p = 0; p < 5; p++){
                int idx = t + (p << 8);
                if (p < 4 || t < 64){
                    int r2 = idx >> 5, c = (idx & 31) << 2;
                    int tau = (r2 >= NJ), r = r2 - NJ*tau;
                    float4 v = *(const float4*)(sXa + tau*2244 + r*XS + c);
                    float s = v.x + v.y + v.z + v.w;
                    float q = v.x*v.x + v.y*v.y + v.z*v.z + v.w*v.w;
                    #pragma unroll
                    for (int m = 1; m <= 16; m <<= 1){ s += __shfl_xor(s, m); q += __shfl_xor(q, m); }
                    float mu = s * (1.f/128.f);
                    float rs = rsqrtf(q * (1.f/128.f) - mu*mu + 1e-5f);
                    float4 g = *(const float4*)(sLG + c);
                    float4 b = *(const float4*)(sLBt + c);
                    float n0 = (v.x-mu)*rs*g.x + b.x, n1 = (v.y-mu)*rs*g.y + b.y;
                    float n2 = (v.z-mu)*rs*g.z + b.z, n3 = (v.w-mu)*rs*g.w + b.w;
                    uint_t h0 = f2bf(n0), h1 = f2bf(n1), h2 = f2bf(n2), h3 = f2bf(n3);
                    uint2 ph; ph.x = h0 | (h1 << 16); ph.y = h2 | (h3 << 16);
                    *(uint2*)(sXh + tau*2312 + r*XBS + c) = ph;
                    float4 a = *(const float4*)(sAW + c);
                    float sp = n0*a.x + n1*a.y + n2*a.z + n3*a.w;
                    #pragma unroll
                    for (int m = 1; m <= 16; m <<= 1) sp += __shfl_xor(sp, m);
                    if ((t & 31) == 0) sK[tau*18 + r] = 1.f / (1.f + expf(-(sp + abv)));
                }
            }
        }
        __syncthreads();

        // ---- (b) MFMA GEMM (pure bf16): B0/B1 = tokens' rows 0..15; B2 = rows 16 ----
        {
            short8 B0h[4], B1h[4], B2h[4];
            const int fo = l16*XBS + quad*8;
            #pragma unroll
            for (int ks = 0; ks < 4; ks++){
                B0h[ks] = *(const short8*)(sXh + fo + ks*32);
                B1h[ks] = *(const short8*)(sXh + 2312 + fo + ks*32);
            }
            const int btau = l16 & 1;   // col 0 -> t0 row16, col 1 -> t1 row16 (others dup, unused)
            const int f16o = btau*2312 + 16*XBS + quad*8;
            #pragma unroll
            for (int ks = 0; ks < 4; ks++)
                B2h[ks] = *(const short8*)(sXh + f16o + ks*32);
            // sXh now dead; sRb aliases it -> all waves must pass here before writes
            __syncthreads();
            const int fbase = wave * 160;
            #pragma unroll 2
            for (int ft = 0; ft < 10; ft++){
                int f0 = fbase + ft*16;
                const ushort_t* ah = whi + (f0 + l16)*128 + quad*8;
                short8 Ah[4];
                #pragma unroll
                for (int ks = 0; ks < 4; ks++)
                    Ah[ks] = *(const short8*)(ah + ks*32);
                float4 bb = *(const float4*)(bcat + f0 + quad*4);
                f32x4 a0, a1, a2;
                a0[0] = bb.x; a0[1] = bb.y; a0[2] = bb.z; a0[3] = bb.w;
                a1 = a0; a2 = a0;
                #pragma unroll
                for (int ks = 0; ks < 4; ks++){
                    a0 = __builtin_amdgcn_mfma_f32_16x16x32_bf16(Ah[ks], B0h[ks], a0, 0, 0, 0);
                    a1 = __builtin_amdgcn_mfma_f32_16x16x32_bf16(Ah[ks], B1h[ks], a1, 0, 0, 0);
                    a2 = __builtin_amdgcn_mfma_f32_16x16x32_bf16(Ah[ks], B2h[ks], a2, 0, 0, 0);
                }
                int fb = f0 + quad*4;
                if (f0 < 512){
                    ushort_t* bse; int col;
                    if (f0 < 256){ bse = sLb; col = fb; } else { bse = sRb; col = fb - 256; }
                    uint2 p0;
                    p0.x = f2bf(a0[0]) | (f2bf(a0[1]) << 16);
                    p0.y = f2bf(a0[2]) | (f2bf(a0[3]) << 16);
                    *(uint2*)(bse + l16*LBS + col) = p0;
                    uint2 p1;
                    p1.x = f2bf(a1[0]) | (f2bf(a1[1]) << 16);
                    p1.y = f2bf(a1[2]) | (f2bf(a1[3]) << 16);
                    *(uint2*)(bse + 4488 + l16*LBS + col) = p1;
                    if (l16 < 2){
                        uint2 p2;
                        p2.x = f2bf(a2[0]) | (f2bf(a2[1]) << 16);
                        p2.y = f2bf(a2[2]) | (f2bf(a2[3]) << 16);
                        *(uint2*)(bse + btau*4488 + 16*LBS + col) = p2;
                    }
                } else {
                    int col = fb - 512;
                    uint2 q0;
                    q0.x = f2bf(a0[0]) | (f2bf(a0[1]) << 16);
                    q0.y = f2bf(a0[2]) | (f2bf(a0[3]) << 16);
                    *(uint2*)(sVb + l16*XBS + col) = q0;
                    uint2 q1;
                    q1.x = f2bf(a1[0]) | (f2bf(a1[1]) << 16);
                    q1.y = f2bf(a1[2]) | (f2bf(a1[3]) << 16);
                    *(uint2*)(sVb + 2312 + l16*XBS + col) = q1;
                    if (l16 < 2){
                        uint2 q2;
                        q2.x = f2bf(a2[0]) | (f2bf(a2[1]) << 16);
                        q2.y = f2bf(a2[2]) | (f2bf(a2[3]) << 16);
                        *(uint2*)(sVb + btau*2312 + 16*XBS + col) = q2;
                    }
                }
            }
        }
        __syncthreads();

        // ---- (c) attention scores: 2 tok x 2 head x 49 pairs = 196 tasks ----
        // Stage 1: read sLb/sRb into regs. Stage 2 (after barrier): write sS over sRb.
        {
            float accv = 0.f; int sidx = 0;
            if (t < 196){
                int tau = (t >= 98); int th = t - 98*tau;
                int h = (th >= 49);  int p = th - 49*h;
                unsigned short pr = PAIR[p];
                int i = pr >> 8, j = pr & 255;
                const uint4* lp = (const uint4*)(sLb + tau*4488 + i*LBS + h*128);
                const uint4* rp = (const uint4*)(sRb + tau*4488 + j*LBS + h*128);
                float accA = 0.f, accB = 0.f;   // 2 chains to halve dep latency
                #pragma unroll
                for (int d = 0; d < 16; d++){
                    uint4 lu = lp[d], ru = rp[d];
                    float4 p0 = *(const float4*)(sPW + d*8);
                    float4 p1 = *(const float4*)(sPW + d*8 + 4);
                    accA += lrelu02(bflo(lu.x) + bflo(ru.x)) * p0.x;
                    accB += lrelu02(bfhi(lu.x) + bfhi(ru.x)) * p0.y;
                    accA += lrelu02(bflo(lu.y) + bflo(ru.y)) * p0.z;
                    accB += lrelu02(bfhi(lu.y) + bfhi(ru.y)) * p0.w;
                    accA += lrelu02(bflo(lu.z) + bflo(ru.z)) * p1.x;
                    accB += lrelu02(bfhi(lu.z) + bfhi(ru.z)) * p1.y;
                    accA += lrelu02(bflo(lu.w) + bflo(ru.w)) * p1.z;
                    accB += lrelu02(bfhi(lu.w) + bfhi(ru.w)) * p1.w;
                }
                accv = accA + accB + psbv;
                sidx = tau*578 + (h*NJ + i)*SS + j;
            }
            __syncthreads();   // drain all sLb/sRb reads before sS overlays sRb
            if (t < 196) sS[sidx] = accv;
        }
        __syncthreads();

        // ---- (d) masked softmax: 2 tok x 34 rows, 2 lanes/row parity split ----
        if (t < 136){
            int rid = t >> 1, sub = t & 1;
            int tau = (rid >= 34); int r34 = rid - 34*tau;
            int h = (r34 >= NJ);   int i = r34 - NJ*h;
            float* sp = sS + tau*578 + (h*NJ + i)*SS;
            unsigned int m = ADJM[i];
            float mx = -1e30f;
            #pragma unroll
            for (int jj = 0; jj < 9; jj++){
                int j = 2*jj + sub;
                if (j < NJ && ((m >> j) & 1u)) mx = fmaxf(mx, sp[j]);
            }
            mx = fmaxf(mx, __shfl_xor(mx, 1));
            float pv[9]; float sum = 0.f;
            #pragma unroll
            for (int jj = 0; jj < 9; jj++){
                int j = 2*jj + sub;
                if (j < NJ && ((m >> j) & 1u)){ pv[jj] = expf(sp[j] - mx); sum += pv[jj]; }
                else pv[jj] = 0.f;
            }
            sum += __shfl_xor(sum, 1);
            float inv = 1.f / sum;
            #pragma unroll
            for (int jj = 0; jj < 9; jj++){
                int j = 2*jj + sub;
                if (j < NJ) sp[j] = pv[jj]*inv;
            }
        }
        __syncthreads();

        // ---- (e) PV (bf16 V) + gelu + blend (x0 from out) -> new x in sX ----
        #pragma unroll
        for (int p = 0; p < 5; p++){
            int idx = t + (p << 8);
            if (p < 4 || t < 64){
                int r2 = idx >> 5, cg = idx & 31;
                int tau = (r2 >= NJ), r = r2 - NJ*tau;
                int c = cg << 2, h = cg >> 4;
                float4 x0v = *(const float4*)(out + base + idx*4);   // issue early; L2-hot
                const float* sp = sS + tau*578 + (h*NJ + r)*SS;
                const ushort_t* vp = sVb + tau*2312 + c;
                float a0 = 0.f, a1 = 0.f, a2 = 0.f, a3 = 0.f;
                #pragma unroll
                for (int j = 0; j < NJ; j++){
                    float pj = sp[j];
                    uint2 vv = *(const uint2*)(vp + j*XBS);
                    a0 += pj*bflo(vv.x); a1 += pj*bfhi(vv.x);
                    a2 += pj*bflo(vv.y); a3 += pj*bfhi(vv.y);
                }
                a0 = gelu_exact(a0); a1 = gelu_exact(a1); a2 = gelu_exact(a2); a3 = gelu_exact(a3);
                float sk = sK[tau*18 + r];
                float4 nx;
                nx.x = (1.f-sk)*a0 + sk*x0v.x;  nx.y = (1.f-sk)*a1 + sk*x0v.y;
                nx.z = (1.f-sk)*a2 + sk*x0v.z;  nx.w = (1.f-sk)*a3 + sk*x0v.w;
                *(float4*)(sXa + tau*2244 + r*XS + c) = nx;
            }
        }
        __syncthreads();
    }

    // ---- store (overwrites the x0 copy) ----
    for (int idx = t; idx < 1088; idx += 256){
        int r2 = idx >> 5, c = (idx & 31) << 2;
        int tau = (r2 >= NJ), r = r2 - NJ*tau;
        *(float4*)(out + base + idx*4) = *(const float4*)(sXa + tau*2244 + r*XS + c);
    }
}

extern "C" void kernel_launch(void* const* d_in, const int* in_sizes, int n_in,
                              void* d_out, int out_size, void* d_ws, size_t ws_size,
                              hipStream_t stream) {
    const float* x   = (const float*)d_in[0];
    const float* og  = (const float*)d_in[1];
    const float* ob  = (const float*)d_in[2];
    const float* lg  = (const float*)d_in[3];
    const float* lb  = (const float*)d_in[4];
    const float* aw  = (const float*)d_in[5];
    const float* ab  = (const float*)d_in[6];
    const float* w1  = (const float*)d_in[7];
    const float* b1  = (const float*)d_in[8];
    const float* w2  = (const float*)d_in[9];
    const float* b2  = (const float*)d_in[10];
    const float* psw = (const float*)d_in[11];
    const float* psb = (const float*)d_in[12];
    const float* vw  = (const float*)d_in[13];
    const float* vb  = (const float*)d_in[14];
    float* out = (float*)d_out;

    // workspace: whi (640*128 bf16) + wlo (640*128 bf16) + bcat (640 f32) = 330,240 B
    ushort_t* whi = (ushort_t*)d_ws;
    ushort_t* wlo = whi + 640*128;
    float* bcat = (float*)(wlo + 640*128);

    prep_kernel<<<dim3(320), dim3(256), 0, stream>>>(w1, b1, w2, b2, vw, vb, whi, wlo, bcat);

    int BT = in_sizes[0] / TOKE;   // 3888 tokens
    appnp_kernel<<<dim3(BT/2), dim3(256), 0, stream>>>(
        x, og, ob, lg, lb, aw, ab, psw, psb, whi, wlo, bcat, out);
}

// Round 11
// 369.683 us; speedup vs baseline: 2.9722x; 1.1542x over previous
//
#include <hip/hip_runtime.h>
#include <math.h>

#define NJ 17
#define XS 132      // fp32 row stride for sX (floats)
#define LBS 264     // ushort row stride for sLb/sRb
#define XBS 136     // ushort row stride for sXh/sVb (16B-aligned rows)
#define SS 17       // score row stride (floats)
#define TOKE (NJ*128)

typedef unsigned short ushort_t;
typedef unsigned int uint_t;
typedef __attribute__((ext_vector_type(8))) short short8;
typedef __attribute__((ext_vector_type(4))) float f32x4;

// adjacency bitmasks (both dirs + diag)
__device__ __constant__ unsigned int ADJM[NJ] = {
    0x93u, 0x7u, 0xEu, 0xCu, 0x31u, 0x70u, 0x60u,
    0x181u, 0x4B80u, 0x700u, 0x600u, 0x1900u, 0x3800u, 0x3000u,
    0xC100u, 0x1C000u, 0x18000u
};
// dense list of the 49 adjacent (i,j) pairs, packed (i<<8)|j
__device__ __constant__ unsigned short PAIR[49] = {
    0x0000,0x0001,0x0004,0x0007, 0x0100,0x0101,0x0102, 0x0201,0x0202,0x0203,
    0x0302,0x0303, 0x0400,0x0404,0x0405, 0x0504,0x0505,0x0506, 0x0605,0x0606,
    0x0700,0x0707,0x0708, 0x0807,0x0808,0x0809,0x080B,0x080E, 0x0908,0x0909,0x090A,
    0x0A09,0x0A0A, 0x0B08,0x0B0B,0x0B0C, 0x0C0B,0x0C0C,0x0C0D, 0x0D0C,0x0D0D,
    0x0E08,0x0E0E,0x0E0F, 0x0F0E,0x0F0F,0x0F10, 0x100F,0x1010
};

__device__ __forceinline__ uint_t f2bf(float v){
    uint_t u = __float_as_uint(v);
    return (u + 0x7FFFu + ((u >> 16) & 1u)) >> 16;
}
__device__ __forceinline__ float bf2f(uint_t h){ return __uint_as_float(h << 16); }
__device__ __forceinline__ float bflo(uint_t u){ return __uint_as_float(u << 16); }
__device__ __forceinline__ float bfhi(uint_t u){ return __uint_as_float(u & 0xFFFF0000u); }
__device__ __forceinline__ float lrelu02(float u){ return fmaxf(u, 0.f) + 0.2f*fminf(u, 0.f); }
__device__ __forceinline__ float gelu_exact(float x){ return 0.5f*x*(1.f + erff(x*0.70710678118654752f)); }

// prep: WT[f][k] bf16-hi (f: 0..255 w1-col, 256..511 w2-col, 512..639 vw-col) + bcat
// (wlo kept in workspace layout for compatibility; unused since r9)
__global__ void prep_kernel(const float* __restrict__ w1, const float* __restrict__ b1,
                            const float* __restrict__ w2, const float* __restrict__ b2,
                            const float* __restrict__ vw, const float* __restrict__ vb,
                            ushort_t* __restrict__ whi, ushort_t* __restrict__ wlo,
                            float* __restrict__ bcat){
    int gid = blockIdx.x*256 + threadIdx.x;
    if (gid < 640*128){
        int f = gid >> 7, k = gid & 127;
        float v;
        if (f < 256)      v = w1[k*256 + f];
        else if (f < 512) v = w2[k*256 + (f-256)];
        else              v = vw[k*128 + (f-512)];
        uint_t h = f2bf(v);
        whi[gid] = (ushort_t)h;
        wlo[gid] = (ushort_t)f2bf(v - bf2f(h));
    }
    if (gid < 640){
        float b;
        if (gid < 256)      b = b1[gid];
        else if (gid < 512) b = b2[gid-256];
        else                b = vb[gid-512];
        bcat[gid] = b;
    }
}

// r11: r10 + amdgpu_waves_per_eu(3) -> VGPR cap 85.
// Occupancy model (11 datapoints, r0..r10): waves/SIMD = floor(256 / VGPR).
//   r10 at VGPR=92 missed the 3-wave boundary (85) by 7 registers; this pins it.
//   Gap is only 92->85 (8%) so rematerialization, not spill, should close it
//   (unlike r5's 170->128 squeeze -> 1 GB scratch). Spill falsifier: FETCH/WRITE jump.
// Everything else byte-identical to r10 (427 us, absmax 0.0234).
// LDS 11,972 f = 47,888 B -> 48,128 alloc (3x = 144,384, r0-proven envelope).
// Alias lifetimes:
//   sLb over sXa      : old x dead after (a); rewritten by (e).
//   sRb over sXh+pad  : xn-hi dead after (b)'s fragment loads (barrier in (b)).
//   sS  over sRb      : l/r dead after (c)'s reads (barrier in (c)).
__attribute__((amdgpu_flat_work_group_size(256, 256), amdgpu_waves_per_eu(3)))
__global__ void appnp_kernel(const float* __restrict__ x,
                  const float* __restrict__ og, const float* __restrict__ ob,
                  const float* __restrict__ lg, const float* __restrict__ lb,
                  const float* __restrict__ aw, const float* __restrict__ ab,
                  const float* __restrict__ psw, const float* __restrict__ psb,
                  const ushort_t* __restrict__ whi, const ushort_t* __restrict__ wlo,
                  const float* __restrict__ bcat,
                  float* __restrict__ out)
{
    __shared__ __align__(16) float smem[11972];
    float*    sXa  = smem;                            // [0,4488)  2x2244 f state x [sLb alias]
    ushort_t* sLb  = (ushort_t*)smem;                 //   2x4488 ush l bf16 (ALIAS sXa)
    ushort_t* sXh  = (ushort_t*)(smem + 4488);        // region B: 2x2312 ush xn bf16-hi
    ushort_t* sRb  = (ushort_t*)(smem + 4488);        //   2x4488 ush r bf16 (ALIAS sXh+pad)
    float*    sS   = smem + 4488;                     //   2x578 f scores (ALIAS sRb, after (c))
    ushort_t* sVb  = (ushort_t*)(smem + 9112);        // [9112,11424) 2x2312 ush V bf16
    float*    sK   = smem + 11424;                    // 2 x 18
    float*    sLG  = smem + 11460;                    // 128
    float*    sLBt = smem + 11588;                    // 128
    float*    sPW  = smem + 11716;                    // 128
    float*    sAW  = smem + 11844;                    // 128  -> total 11,972 f = 47,888 B

    const int t = threadIdx.x;
    const int wave = t >> 6, lane = t & 63, l16 = lane & 15, quad = lane >> 4;
    const long long base = (long long)blockIdx.x * (2*TOKE);

    // uniform scalars (L2-resident s_load)
    const float abv  = ab[0];
    const float psbv = psb[0];

    // ---- stage small params ----
    if (t < 128){ sLG[t] = lg[t]; sLBt[t] = lb[t]; sPW[t] = psw[t]; sAW[t] = aw[t]; }

    // ---- load x for 2 tokens (1088 float4 groups, contiguous) ----
    for (int idx = t; idx < 1088; idx += 256){
        int r2 = idx >> 5, c = (idx & 31) << 2;
        int tau = (r2 >= NJ), r = r2 - NJ*tau;
        *(float4*)(sXa + tau*2244 + r*XS + c) = *(const float4*)(x + base + idx*4);
    }
    __syncthreads();

    // ---- outer LN -> sX in place; x0 copy -> out (global, read back in (e)) ----
    #pragma unroll
    for (int p = 0; p < 5; p++){
        int idx = t + (p << 8);
        if (p < 4 || t < 64){
            int r2 = idx >> 5, c = (idx & 31) << 2;
            int tau = (r2 >= NJ), r = r2 - NJ*tau;
            float* px = sXa + tau*2244 + r*XS + c;
            float4 v = *(float4*)px;
            float s = v.x + v.y + v.z + v.w;
            float q = v.x*v.x + v.y*v.y + v.z*v.z + v.w*v.w;
            #pragma unroll
            for (int m = 1; m <= 16; m <<= 1){ s += __shfl_xor(s, m); q += __shfl_xor(q, m); }
            float mu = s * (1.f/128.f);
            float rs = rsqrtf(q * (1.f/128.f) - mu*mu + 1e-5f);
            float4 g = *(const float4*)(og + c);
            float4 b = *(const float4*)(ob + c);
            float4 nv;
            nv.x = (v.x-mu)*rs*g.x + b.x;  nv.y = (v.y-mu)*rs*g.y + b.y;
            nv.z = (v.z-mu)*rs*g.z + b.z;  nv.w = (v.w-mu)*rs*g.w + b.w;
            *(float4*)px = nv;
            *(float4*)(out + base + idx*4) = nv;   // x0 parked in out until final store
        }
    }
    __syncthreads();

    for (int it = 0; it < 4; it++){
        // ---- (a) inner LN -> sXh bf16 (RTNE) + fused skip gate ----
        {
            #pragma unroll
            for (int p = 0; p < 5; p++){
                int idx = t + (p << 8);
                if (p < 4 || t < 64){
                    int r2 = idx >> 5, c = (idx & 31) << 2;
                    int tau = (r2 >= NJ), r = r2 - NJ*tau;
                    float4 v = *(const float4*)(sXa + tau*2244 + r*XS + c);
                    float s = v.x + v.y + v.z + v.w;
                    float q = v.x*v.x + v.y*v.y + v.z*v.z + v.w*v.w;
                    #pragma unroll
                    for (int m = 1; m <= 16; m <<= 1){ s += __shfl_xor(s, m); q += __shfl_xor(q, m); }
                    float mu = s * (1.f/128.f);
                    float rs = rsqrtf(q * (1.f/128.f) - mu*mu + 1e-5f);
                    float4 g = *(const float4*)(sLG + c);
                    float4 b = *(const float4*)(sLBt + c);
                    float n0 = (v.x-mu)*rs*g.x + b.x, n1 = (v.y-mu)*rs*g.y + b.y;
                    float n2 = (v.z-mu)*rs*g.z + b.z, n3 = (v.w-mu)*rs*g.w + b.w;
                    uint_t h0 = f2bf(n0), h1 = f2bf(n1), h2 = f2bf(n2), h3 = f2bf(n3);
                    uint2 ph; ph.x = h0 | (h1 << 16); ph.y = h2 | (h3 << 16);
                    *(uint2*)(sXh + tau*2312 + r*XBS + c) = ph;
                    float4 a = *(const float4*)(sAW + c);
                    float sp = n0*a.x + n1*a.y + n2*a.z + n3*a.w;
                    #pragma unroll
                    for (int m = 1; m <= 16; m <<= 1) sp += __shfl_xor(sp, m);
                    if ((t & 31) == 0) sK[tau*18 + r] = 1.f / (1.f + expf(-(sp + abv)));
                }
            }
        }
        __syncthreads();

        // ---- (b) MFMA GEMM (pure bf16): B0/B1 = tokens' rows 0..15; B2 = rows 16 ----
        {
            short8 B0h[4], B1h[4], B2h[4];
            const int fo = l16*XBS + quad*8;
            #pragma unroll
            for (int ks = 0; ks < 4; ks++){
                B0h[ks] = *(const short8*)(sXh + fo + ks*32);
                B1h[ks] = *(const short8*)(sXh + 2312 + fo + ks*32);
            }
            const int btau = l16 & 1;   // col 0 -> t0 row16, col 1 -> t1 row16 (others dup, unused)
            const int f16o = btau*2312 + 16*XBS + quad*8;
            #pragma unroll
            for (int ks = 0; ks < 4; ks++)
                B2h[ks] = *(const short8*)(sXh + f16o + ks*32);
            // sXh now dead; sRb aliases it -> all waves must pass here before writes
            __syncthreads();
            const int fbase = wave * 160;
            #pragma unroll 2
            for (int ft = 0; ft < 10; ft++){
                int f0 = fbase + ft*16;
                const ushort_t* ah = whi + (f0 + l16)*128 + quad*8;
                short8 Ah[4];
                #pragma unroll
                for (int ks = 0; ks < 4; ks++)
                    Ah[ks] = *(const short8*)(ah + ks*32);
                float4 bb = *(const float4*)(bcat + f0 + quad*4);
                f32x4 a0, a1, a2;
                a0[0] = bb.x; a0[1] = bb.y; a0[2] = bb.z; a0[3] = bb.w;
                a1 = a0; a2 = a0;
                #pragma unroll
                for (int ks = 0; ks < 4; ks++){
                    a0 = __builtin_amdgcn_mfma_f32_16x16x32_bf16(Ah[ks], B0h[ks], a0, 0, 0, 0);
                    a1 = __builtin_amdgcn_mfma_f32_16x16x32_bf16(Ah[ks], B1h[ks], a1, 0, 0, 0);
                    a2 = __builtin_amdgcn_mfma_f32_16x16x32_bf16(Ah[ks], B2h[ks], a2, 0, 0, 0);
                }
                int fb = f0 + quad*4;
                if (f0 < 512){
                    ushort_t* bse; int col;
                    if (f0 < 256){ bse = sLb; col = fb; } else { bse = sRb; col = fb - 256; }
                    uint2 p0;
                    p0.x = f2bf(a0[0]) | (f2bf(a0[1]) << 16);
                    p0.y = f2bf(a0[2]) | (f2bf(a0[3]) << 16);
                    *(uint2*)(bse + l16*LBS + col) = p0;
                    uint2 p1;
                    p1.x = f2bf(a1[0]) | (f2bf(a1[1]) << 16);
                    p1.y = f2bf(a1[2]) | (f2bf(a1[3]) << 16);
                    *(uint2*)(bse + 4488 + l16*LBS + col) = p1;
                    if (l16 < 2){
                        uint2 p2;
                        p2.x = f2bf(a2[0]) | (f2bf(a2[1]) << 16);
                        p2.y = f2bf(a2[2]) | (f2bf(a2[3]) << 16);
                        *(uint2*)(bse + btau*4488 + 16*LBS + col) = p2;
                    }
                } else {
                    int col = fb - 512;
                    uint2 q0;
                    q0.x = f2bf(a0[0]) | (f2bf(a0[1]) << 16);
                    q0.y = f2bf(a0[2]) | (f2bf(a0[3]) << 16);
                    *(uint2*)(sVb + l16*XBS + col) = q0;
                    uint2 q1;
                    q1.x = f2bf(a1[0]) | (f2bf(a1[1]) << 16);
                    q1.y = f2bf(a1[2]) | (f2bf(a1[3]) << 16);
                    *(uint2*)(sVb + 2312 + l16*XBS + col) = q1;
                    if (l16 < 2){
                        uint2 q2;
                        q2.x = f2bf(a2[0]) | (f2bf(a2[1]) << 16);
                        q2.y = f2bf(a2[2]) | (f2bf(a2[3]) << 16);
                        *(uint2*)(sVb + btau*2312 + 16*XBS + col) = q2;
                    }
                }
            }
        }
        __syncthreads();

        // ---- (c) attention scores: 2 tok x 2 head x 49 pairs = 196 tasks ----
        // Stage 1: read sLb/sRb into regs. Stage 2 (after barrier): write sS over sRb.
        {
            float accv = 0.f; int sidx = 0;
            if (t < 196){
                int tau = (t >= 98); int th = t - 98*tau;
                int h = (th >= 49);  int p = th - 49*h;
                unsigned short pr = PAIR[p];
                int i = pr >> 8, j = pr & 255;
                const uint4* lp = (const uint4*)(sLb + tau*4488 + i*LBS + h*128);
                const uint4* rp = (const uint4*)(sRb + tau*4488 + j*LBS + h*128);
                float accA = 0.f, accB = 0.f;   // 2 chains to halve dep latency
                #pragma unroll
                for (int d = 0; d < 16; d++){
                    uint4 lu = lp[d], ru = rp[d];
                    float4 p0 = *(const float4*)(sPW + d*8);
                    float4 p1 = *(const float4*)(sPW + d*8 + 4);
                    accA += lrelu02(bflo(lu.x) + bflo(ru.x)) * p0.x;
                    accB += lrelu02(bfhi(lu.x) + bfhi(ru.x)) * p0.y;
                    accA += lrelu02(bflo(lu.y) + bflo(ru.y)) * p0.z;
                    accB += lrelu02(bfhi(lu.y) + bfhi(ru.y)) * p0.w;
                    accA += lrelu02(bflo(lu.z) + bflo(ru.z)) * p1.x;
                    accB += lrelu02(bfhi(lu.z) + bfhi(ru.z)) * p1.y;
                    accA += lrelu02(bflo(lu.w) + bflo(ru.w)) * p1.z;
                    accB += lrelu02(bfhi(lu.w) + bfhi(ru.w)) * p1.w;
                }
                accv = accA + accB + psbv;
                sidx = tau*578 + (h*NJ + i)*SS + j;
            }
            __syncthreads();   // drain all sLb/sRb reads before sS overlays sRb
            if (t < 196) sS[sidx] = accv;
        }
        __syncthreads();

        // ---- (d) masked softmax: 2 tok x 34 rows, 2 lanes/row parity split ----
        if (t < 136){
            int rid = t >> 1, sub = t & 1;
            int tau = (rid >= 34); int r34 = rid - 34*tau;
            int h = (r34 >= NJ);   int i = r34 - NJ*h;
            float* sp = sS + tau*578 + (h*NJ + i)*SS;
            unsigned int m = ADJM[i];
            float mx = -1e30f;
            #pragma unroll
            for (int jj = 0; jj < 9; jj++){
                int j = 2*jj + sub;
                if (j < NJ && ((m >> j) & 1u)) mx = fmaxf(mx, sp[j]);
            }
            mx = fmaxf(mx, __shfl_xor(mx, 1));
            float pv[9]; float sum = 0.f;
            #pragma unroll
            for (int jj = 0; jj < 9; jj++){
                int j = 2*jj + sub;
                if (j < NJ && ((m >> j) & 1u)){ pv[jj] = expf(sp[j] - mx); sum += pv[jj]; }
                else pv[jj] = 0.f;
            }
            sum += __shfl_xor(sum, 1);
            float inv = 1.f / sum;
            #pragma unroll
            for (int jj = 0; jj < 9; jj++){
                int j = 2*jj + sub;
                if (j < NJ) sp[j] = pv[jj]*inv;
            }
        }
        __syncthreads();

        // ---- (e) PV (bf16 V) + gelu + blend (x0 from out) -> new x in sX ----
        #pragma unroll
        for (int p = 0; p < 5; p++){
            int idx = t + (p << 8);
            if (p < 4 || t < 64){
                int r2 = idx >> 5, cg = idx & 31;
                int tau = (r2 >= NJ), r = r2 - NJ*tau;
                int c = cg << 2, h = cg >> 4;
                float4 x0v = *(const float4*)(out + base + idx*4);   // issue early; L2-hot
                const float* sp = sS + tau*578 + (h*NJ + r)*SS;
                const ushort_t* vp = sVb + tau*2312 + c;
                float a0 = 0.f, a1 = 0.f, a2 = 0.f, a3 = 0.f;
                #pragma unroll
                for (int j = 0; j < NJ; j++){
                    float pj = sp[j];
                    uint2 vv = *(const uint2*)(vp + j*XBS);
                    a0 += pj*bflo(vv.x); a1 += pj*bfhi(vv.x);
                    a2 += pj*bflo(vv.y); a3 += pj*bfhi(vv.y);
                }
                a0 = gelu_exact(a0); a1 = gelu_exact(a1); a2 = gelu_exact(a2); a3 = gelu_exact(a3);
                float sk = sK[tau*18 + r];
                float4 nx;
                nx.x = (1.f-sk)*a0 + sk*x0v.x;  nx.y = (1.f-sk)*a1 + sk*x0v.y;
                nx.z = (1.f-sk)*a2 + sk*x0v.z;  nx.w = (1.f-sk)*a3 + sk*x0v.w;
                *(float4*)(sXa + tau*2244 + r*XS + c) = nx;
            }
        }
        __syncthreads();
    }

    // ---- store (overwrites the x0 copy) ----
    for (int idx = t; idx < 1088; idx += 256){
        int r2 = idx >> 5, c = (idx & 31) << 2;
        int tau = (r2 >= NJ), r = r2 - NJ*tau;
        *(float4*)(out + base + idx*4) = *(const float4*)(sXa + tau*2244 + r*XS + c);
    }
}

extern "C" void kernel_launch(void* const* d_in, const int* in_sizes, int n_in,
                              void* d_out, int out_size, void* d_ws, size_t ws_size,
                              hipStream_t stream) {
    const float* x   = (const float*)d_in[0];
    const float* og  = (const float*)d_in[1];
    const float* ob  = (const float*)d_in[2];
    const float* lg  = (const float*)d_in[3];
    const float* lb  = (const float*)d_in[4];
    const float* aw  = (const float*)d_in[5];
    const float* ab  = (const float*)d_in[6];
    const float* w1  = (const float*)d_in[7];
    const float* b1  = (const float*)d_in[8];
    const float* w2  = (const float*)d_in[9];
    const float* b2  = (const float*)d_in[10];
    const float* psw = (const float*)d_in[11];
    const float* psb = (const float*)d_in[12];
    const float* vw  = (const float*)d_in[13];
    const float* vb  = (const float*)d_in[14];
    float* out = (float*)d_out;

    // workspace: whi (640*128 bf16) + wlo (640*128 bf16) + bcat (640 f32) = 330,240 B
    ushort_t* whi = (ushort_t*)d_ws;
    ushort_t* wlo = whi + 640*128;
    float* bcat = (float*)(wlo + 640*128);

    prep_kernel<<<dim3(320), dim3(256), 0, stream>>>(w1, b1, w2, b2, vw, vb, whi, wlo, bcat);

    int BT = in_sizes[0] / TOKE;   // 3888 tokens
    appnp_kernel<<<dim3(BT/2), dim3(256), 0, stream>>>(
        x, og, ob, lg, lb, aw, ab, psw, psb, whi, wlo, bcat, out);
}